// Round 1
// baseline (355.685 us; speedup 1.0000x reference)
//
#include <hip/hip_runtime.h>

#define FDIM 1000
#define BDIM 2049
#define NTH  256
#define NF   4   // ceil(FDIM / NTH)

// out layout (concatenated): y_out (F,B,C,2,S) | v (F,B,S) | R (B,C,C,2,S)
#define V_OFF 32784000ull
#define R_OFF 40980000ull

__global__ __launch_bounds__(NTH, 2) void Separator_55791625175550_kernel(
    const float* __restrict__ y,
    const float* __restrict__ x,
    const int*   __restrict__ itp,
    float*       __restrict__ out)
{
    const float EPSF = 1.1920928955078125e-07f;   // np.finfo(float32).eps
    const float REGC = 3.4526698300124393e-04f;   // sqrt(eps)

    const int b    = blockIdx.x;
    const int tid  = threadIdx.x;
    const int lane = tid & 63;
    const int wid  = tid >> 6;

    const int  iters   = itp[0];
    const int  nloops  = (iters > 0) ? iters : 1;
    const bool zero_it = (iters == 0);

    __shared__ float red[4][20];
    __shared__ float rsum[20];   // raw block sums
    __shared__ float rnorm[16];  // R / (eps + sum_f v)

    // register-resident state: yc (complex, [k][c][s]) and xc (complex, [k][c])
    float y0r[NF][4], y0i[NF][4], y1r[NF][4], y1i[NF][4];
    float xr0[NF], xi0[NF], xr1[NF], xi1[NF];
    float v[NF][4];

    // ---- load: per f, the 16 floats (c,ri,s) are one contiguous 64B line ----
    #pragma unroll
    for (int k = 0; k < NF; ++k) {
        const int f = tid + k * NTH;
        if (f < FDIM) {
            const float4* yp = reinterpret_cast<const float4*>(y) + (size_t)(f * BDIM + b) * 4;
            float4 a0 = yp[0];  // c0 re s0..3
            float4 a1 = yp[1];  // c0 im
            float4 a2 = yp[2];  // c1 re
            float4 a3 = yp[3];  // c1 im
            y0r[k][0]=a0.x; y0r[k][1]=a0.y; y0r[k][2]=a0.z; y0r[k][3]=a0.w;
            y0i[k][0]=a1.x; y0i[k][1]=a1.y; y0i[k][2]=a1.z; y0i[k][3]=a1.w;
            y1r[k][0]=a2.x; y1r[k][1]=a2.y; y1r[k][2]=a2.z; y1r[k][3]=a2.w;
            y1i[k][0]=a3.x; y1i[k][1]=a3.y; y1i[k][2]=a3.z; y1i[k][3]=a3.w;
            float4 xv = reinterpret_cast<const float4*>(x)[(size_t)(f * BDIM + b)];
            xr0[k]=xv.x; xi0[k]=xv.y; xr1[k]=xv.z; xi1[k]=xv.w;
        } else {
            #pragma unroll
            for (int s = 0; s < 4; ++s) { y0r[k][s]=0.f; y0i[k][s]=0.f; y1r[k][s]=0.f; y1i[k][s]=0.f; }
            xr0[k]=0.f; xi0[k]=0.f; xr1[k]=0.f; xi1[k]=0.f;
        }
    }

    for (int it = 0; it < nloops; ++it) {
        const bool last = (it == nloops - 1);

        // ---- phase A: v and local Hermitian R + sum_f v ----
        float a00[4], a11[4], a01r[4], a01i[4], sv[4];
        #pragma unroll
        for (int s = 0; s < 4; ++s) { a00[s]=0.f; a11[s]=0.f; a01r[s]=0.f; a01i[s]=0.f; sv[s]=0.f; }
        #pragma unroll
        for (int k = 0; k < NF; ++k) {
            #pragma unroll
            for (int s = 0; s < 4; ++s) {
                const float p0 = y0r[k][s]*y0r[k][s] + y0i[k][s]*y0i[k][s];
                const float p1 = y1r[k][s]*y1r[k][s] + y1i[k][s]*y1i[k][s];
                v[k][s] = 0.5f * (p0 + p1);
                a00[s] += p0;
                a11[s] += p1;
                a01r[s] += y0r[k][s]*y1r[k][s] + y0i[k][s]*y1i[k][s];  // Re(yc0*conj(yc1))
                a01i[s] += y0i[k][s]*y1r[k][s] - y0r[k][s]*y1i[k][s];  // Im(yc0*conj(yc1))
                sv[s]   += v[k][s];
            }
        }

        // ---- block reduce 20 scalars: wave butterfly + cross-wave via LDS ----
        float vals[20];
        #pragma unroll
        for (int s = 0; s < 4; ++s) {
            vals[s]=a00[s]; vals[4+s]=a11[s]; vals[8+s]=a01r[s]; vals[12+s]=a01i[s]; vals[16+s]=sv[s];
        }
        #pragma unroll
        for (int j = 0; j < 20; ++j) {
            float t = vals[j];
            t += __shfl_xor(t, 1);  t += __shfl_xor(t, 2);  t += __shfl_xor(t, 4);
            t += __shfl_xor(t, 8);  t += __shfl_xor(t, 16); t += __shfl_xor(t, 32);
            vals[j] = t;
        }
        if (lane == 0) {
            #pragma unroll
            for (int j = 0; j < 20; ++j) red[wid][j] = vals[j];
        }
        __syncthreads();
        if (tid < 20) rsum[tid] = red[0][tid] + red[1][tid] + red[2][tid] + red[3][tid];
        __syncthreads();
        if (tid < 16) rnorm[tid] = rsum[tid] / (EPSF + rsum[16 + (tid & 3)]);
        __syncthreads();

        float rn00[4], rn11[4], rn01r[4], rn01i[4];
        #pragma unroll
        for (int s = 0; s < 4; ++s) {
            rn00[s]=rnorm[s]; rn11[s]=rnorm[4+s]; rn01r[s]=rnorm[8+s]; rn01i[s]=rnorm[12+s];
        }

        // ---- last-iteration outputs: v (per f) and R (per b) ----
        if (last) {
            #pragma unroll
            for (int k = 0; k < NF; ++k) {
                const int f = tid + k * NTH;
                if (f < FDIM) {
                    float4 vv = make_float4(v[k][0], v[k][1], v[k][2], v[k][3]);
                    *reinterpret_cast<float4*>(out + V_OFF + (size_t)(f * BDIM + b) * 4) = vv;
                }
            }
            if (tid < 32) {
                const int c  = (tid >> 4) & 1;
                const int d  = (tid >> 3) & 1;
                const int ri = (tid >> 2) & 1;
                const int s  = tid & 3;
                const float* src = zero_it ? rsum : rnorm;
                float val;
                if (c == d) val = ri ? 0.0f : src[(c ? 4 : 0) + s];
                else if (c == 0) val = ri ?  src[12 + s] : src[8 + s];   // R01
                else             val = ri ? -src[12 + s] : src[8 + s];   // R10 = conj(R01)
                out[R_OFF + (size_t)b * 32 + tid] = val;
            }
        }

        // ---- phase C: per-f 2x2 Hermitian solve + Wiener filter ----
        if (!zero_it) {
            #pragma unroll
            for (int k = 0; k < NF; ++k) {
                const int f = tid + k * NTH;
                if (f < FDIM) {
                    float c00 = REGC, c11 = REGC, c01r = 0.f, c01i = 0.f;
                    #pragma unroll
                    for (int s = 0; s < 4; ++s) {
                        c00  += v[k][s] * rn00[s];
                        c11  += v[k][s] * rn11[s];
                        c01r += v[k][s] * rn01r[s];
                        c01i += v[k][s] * rn01i[s];
                    }
                    const float det  = c00 * c11 - (c01r * c01r + c01i * c01i);  // real, >0 (reg)
                    const float invd = det / (det * det);                         // matches conj(det)/|det|^2
                    const float i00 = invd * c11, i11 = invd * c00;
                    const float i01r = -invd * c01r, i01i = -invd * c01i;
                    // w = Cxx^-1 @ xc  (i10 = conj(i01))
                    const float w0r = i00 * xr0[k] + (i01r * xr1[k] - i01i * xi1[k]);
                    const float w0i = i00 * xi0[k] + (i01r * xi1[k] + i01i * xr1[k]);
                    const float w1r = (i01r * xr0[k] + i01i * xi0[k]) + i11 * xr1[k];
                    const float w1i = (i01r * xi0[k] - i01i * xr0[k]) + i11 * xi1[k];
                    #pragma unroll
                    for (int s = 0; s < 4; ++s) {
                        const float vs = v[k][s];
                        y0r[k][s] = vs * (rn00[s] * w0r + (rn01r[s] * w1r - rn01i[s] * w1i));
                        y0i[k][s] = vs * (rn00[s] * w0i + (rn01r[s] * w1i + rn01i[s] * w1r));
                        y1r[k][s] = vs * ((rn01r[s] * w0r + rn01i[s] * w0i) + rn11[s] * w1r);
                        y1i[k][s] = vs * ((rn01r[s] * w0i - rn01i[s] * w0r) + rn11[s] * w1i);
                    }
                }
            }
        }
    }

    // ---- write y_out ----
    #pragma unroll
    for (int k = 0; k < NF; ++k) {
        const int f = tid + k * NTH;
        if (f < FDIM) {
            float4* op = reinterpret_cast<float4*>(out) + (size_t)(f * BDIM + b) * 4;
            op[0] = make_float4(y0r[k][0], y0r[k][1], y0r[k][2], y0r[k][3]);
            op[1] = make_float4(y0i[k][0], y0i[k][1], y0i[k][2], y0i[k][3]);
            op[2] = make_float4(y1r[k][0], y1r[k][1], y1r[k][2], y1r[k][3]);
            op[3] = make_float4(y1i[k][0], y1i[k][1], y1i[k][2], y1i[k][3]);
        }
    }
}

extern "C" void kernel_launch(void* const* d_in, const int* in_sizes, int n_in,
                              void* d_out, int out_size, void* d_ws, size_t ws_size,
                              hipStream_t stream) {
    const float* y   = (const float*)d_in[0];
    const float* x   = (const float*)d_in[1];
    const int*   itp = (const int*)d_in[2];
    float* out = (float*)d_out;
    Separator_55791625175550_kernel<<<BDIM, NTH, 0, stream>>>(y, x, itp, out);
}

// Round 2
// 349.619 us; speedup vs baseline: 1.0173x; 1.0173x over previous
//
#include <hip/hip_runtime.h>

#define FDIM 1000
#define BDIM 2049
#define NTH  256
#define NF   4   // ceil(FDIM / NTH)

// XCD-aware swizzle: 8 XCDs, contiguous b-chunks of 257 per XCD so that
// adjacent b's (sharing 128B L2 lines in y/y_out/x/v) land on the same XCD.
#define NXCD   8
#define BCHUNK 257
#define GRID   (NXCD * BCHUNK)   // 2056, blocks with b>=2049 exit

// out layout (concatenated): y_out (F,B,C,2,S) | v (F,B,S) | R (B,C,C,2,S)
#define V_OFF 32784000ull
#define R_OFF 40980000ull

__global__ __launch_bounds__(NTH, 2) void Separator_55791625175550_kernel(
    const float* __restrict__ y,
    const float* __restrict__ x,
    const int*   __restrict__ itp,
    float*       __restrict__ out)
{
    const float EPSF = 1.1920928955078125e-07f;   // np.finfo(float32).eps
    const float REGC = 3.4526698300124393e-04f;   // sqrt(eps)

    // b = (blockIdx%8)*257 + blockIdx/8  -> adjacent b on same XCD
    const int b = (blockIdx.x & (NXCD - 1)) * BCHUNK + (blockIdx.x >> 3);
    if (b >= BDIM) return;

    const int tid  = threadIdx.x;
    const int lane = tid & 63;
    const int wid  = tid >> 6;

    const int  iters   = itp[0];
    const int  nloops  = (iters > 0) ? iters : 1;
    const bool zero_it = (iters == 0);

    __shared__ float red[4][20];
    __shared__ float rsum[20];   // raw block sums
    __shared__ float rnorm[16];  // R / (eps + sum_f v)

    // register-resident state: yc (complex, [k][c][s]) and xc (complex, [k][c])
    float y0r[NF][4], y0i[NF][4], y1r[NF][4], y1i[NF][4];
    float xr0[NF], xi0[NF], xr1[NF], xi1[NF];
    float v[NF][4];

    // ---- load: per f, the 16 floats (c,ri,s) are one contiguous 64B line ----
    #pragma unroll
    for (int k = 0; k < NF; ++k) {
        const int f = tid + k * NTH;
        if (f < FDIM) {
            const float4* yp = reinterpret_cast<const float4*>(y) + (size_t)(f * BDIM + b) * 4;
            float4 a0 = yp[0];  // c0 re s0..3
            float4 a1 = yp[1];  // c0 im
            float4 a2 = yp[2];  // c1 re
            float4 a3 = yp[3];  // c1 im
            y0r[k][0]=a0.x; y0r[k][1]=a0.y; y0r[k][2]=a0.z; y0r[k][3]=a0.w;
            y0i[k][0]=a1.x; y0i[k][1]=a1.y; y0i[k][2]=a1.z; y0i[k][3]=a1.w;
            y1r[k][0]=a2.x; y1r[k][1]=a2.y; y1r[k][2]=a2.z; y1r[k][3]=a2.w;
            y1i[k][0]=a3.x; y1i[k][1]=a3.y; y1i[k][2]=a3.z; y1i[k][3]=a3.w;
            float4 xv = reinterpret_cast<const float4*>(x)[(size_t)(f * BDIM + b)];
            xr0[k]=xv.x; xi0[k]=xv.y; xr1[k]=xv.z; xi1[k]=xv.w;
        } else {
            #pragma unroll
            for (int s = 0; s < 4; ++s) { y0r[k][s]=0.f; y0i[k][s]=0.f; y1r[k][s]=0.f; y1i[k][s]=0.f; }
            xr0[k]=0.f; xi0[k]=0.f; xr1[k]=0.f; xi1[k]=0.f;
        }
    }

    for (int it = 0; it < nloops; ++it) {
        const bool last = (it == nloops - 1);

        // ---- phase A: v and local Hermitian R + sum_f v ----
        float a00[4], a11[4], a01r[4], a01i[4], sv[4];
        #pragma unroll
        for (int s = 0; s < 4; ++s) { a00[s]=0.f; a11[s]=0.f; a01r[s]=0.f; a01i[s]=0.f; sv[s]=0.f; }
        #pragma unroll
        for (int k = 0; k < NF; ++k) {
            #pragma unroll
            for (int s = 0; s < 4; ++s) {
                const float p0 = y0r[k][s]*y0r[k][s] + y0i[k][s]*y0i[k][s];
                const float p1 = y1r[k][s]*y1r[k][s] + y1i[k][s]*y1i[k][s];
                v[k][s] = 0.5f * (p0 + p1);
                a00[s] += p0;
                a11[s] += p1;
                a01r[s] += y0r[k][s]*y1r[k][s] + y0i[k][s]*y1i[k][s];  // Re(yc0*conj(yc1))
                a01i[s] += y0i[k][s]*y1r[k][s] - y0r[k][s]*y1i[k][s];  // Im(yc0*conj(yc1))
                sv[s]   += v[k][s];
            }
        }

        // ---- block reduce 20 scalars: wave butterfly + cross-wave via LDS ----
        float vals[20];
        #pragma unroll
        for (int s = 0; s < 4; ++s) {
            vals[s]=a00[s]; vals[4+s]=a11[s]; vals[8+s]=a01r[s]; vals[12+s]=a01i[s]; vals[16+s]=sv[s];
        }
        #pragma unroll
        for (int j = 0; j < 20; ++j) {
            float t = vals[j];
            t += __shfl_xor(t, 1);  t += __shfl_xor(t, 2);  t += __shfl_xor(t, 4);
            t += __shfl_xor(t, 8);  t += __shfl_xor(t, 16); t += __shfl_xor(t, 32);
            vals[j] = t;
        }
        if (lane == 0) {
            #pragma unroll
            for (int j = 0; j < 20; ++j) red[wid][j] = vals[j];
        }
        __syncthreads();
        if (tid < 20) rsum[tid] = red[0][tid] + red[1][tid] + red[2][tid] + red[3][tid];
        __syncthreads();
        if (tid < 16) rnorm[tid] = rsum[tid] / (EPSF + rsum[16 + (tid & 3)]);
        __syncthreads();

        float rn00[4], rn11[4], rn01r[4], rn01i[4];
        #pragma unroll
        for (int s = 0; s < 4; ++s) {
            rn00[s]=rnorm[s]; rn11[s]=rnorm[4+s]; rn01r[s]=rnorm[8+s]; rn01i[s]=rnorm[12+s];
        }

        // ---- last-iteration outputs: v (per f) and R (per b) ----
        if (last) {
            #pragma unroll
            for (int k = 0; k < NF; ++k) {
                const int f = tid + k * NTH;
                if (f < FDIM) {
                    float4 vv = make_float4(v[k][0], v[k][1], v[k][2], v[k][3]);
                    *reinterpret_cast<float4*>(out + V_OFF + (size_t)(f * BDIM + b) * 4) = vv;
                }
            }
            if (tid < 32) {
                const int c  = (tid >> 4) & 1;
                const int d  = (tid >> 3) & 1;
                const int ri = (tid >> 2) & 1;
                const int s  = tid & 3;
                const float* src = zero_it ? rsum : rnorm;
                float val;
                if (c == d) val = ri ? 0.0f : src[(c ? 4 : 0) + s];
                else if (c == 0) val = ri ?  src[12 + s] : src[8 + s];   // R01
                else             val = ri ? -src[12 + s] : src[8 + s];   // R10 = conj(R01)
                out[R_OFF + (size_t)b * 32 + tid] = val;
            }
        }

        // ---- phase C: per-f 2x2 Hermitian solve + Wiener filter ----
        if (!zero_it) {
            #pragma unroll
            for (int k = 0; k < NF; ++k) {
                const int f = tid + k * NTH;
                if (f < FDIM) {
                    float c00 = REGC, c11 = REGC, c01r = 0.f, c01i = 0.f;
                    #pragma unroll
                    for (int s = 0; s < 4; ++s) {
                        c00  += v[k][s] * rn00[s];
                        c11  += v[k][s] * rn11[s];
                        c01r += v[k][s] * rn01r[s];
                        c01i += v[k][s] * rn01i[s];
                    }
                    const float det  = c00 * c11 - (c01r * c01r + c01i * c01i);  // real, >0 (reg)
                    const float invd = det / (det * det);                         // matches conj(det)/|det|^2
                    const float i00 = invd * c11, i11 = invd * c00;
                    const float i01r = -invd * c01r, i01i = -invd * c01i;
                    // w = Cxx^-1 @ xc  (i10 = conj(i01))
                    const float w0r = i00 * xr0[k] + (i01r * xr1[k] - i01i * xi1[k]);
                    const float w0i = i00 * xi0[k] + (i01r * xi1[k] + i01i * xr1[k]);
                    const float w1r = (i01r * xr0[k] + i01i * xi0[k]) + i11 * xr1[k];
                    const float w1i = (i01r * xi0[k] - i01i * xr0[k]) + i11 * xi1[k];
                    #pragma unroll
                    for (int s = 0; s < 4; ++s) {
                        const float vs = v[k][s];
                        y0r[k][s] = vs * (rn00[s] * w0r + (rn01r[s] * w1r - rn01i[s] * w1i));
                        y0i[k][s] = vs * (rn00[s] * w0i + (rn01r[s] * w1i + rn01i[s] * w1r));
                        y1r[k][s] = vs * ((rn01r[s] * w0r + rn01i[s] * w0i) + rn11[s] * w1r);
                        y1i[k][s] = vs * ((rn01r[s] * w0i - rn01i[s] * w0r) + rn11[s] * w1i);
                    }
                }
            }
        }
    }

    // ---- write y_out ----
    #pragma unroll
    for (int k = 0; k < NF; ++k) {
        const int f = tid + k * NTH;
        if (f < FDIM) {
            float4* op = reinterpret_cast<float4*>(out) + (size_t)(f * BDIM + b) * 4;
            op[0] = make_float4(y0r[k][0], y0r[k][1], y0r[k][2], y0r[k][3]);
            op[1] = make_float4(y0i[k][0], y0i[k][1], y0i[k][2], y0i[k][3]);
            op[2] = make_float4(y1r[k][0], y1r[k][1], y1r[k][2], y1r[k][3]);
            op[3] = make_float4(y1i[k][0], y1i[k][1], y1i[k][2], y1i[k][3]);
        }
    }
}

extern "C" void kernel_launch(void* const* d_in, const int* in_sizes, int n_in,
                              void* d_out, int out_size, void* d_ws, size_t ws_size,
                              hipStream_t stream) {
    const float* y   = (const float*)d_in[0];
    const float* x   = (const float*)d_in[1];
    const int*   itp = (const int*)d_in[2];
    float* out = (float*)d_out;
    Separator_55791625175550_kernel<<<GRID, NTH, 0, stream>>>(y, x, itp, out);
}

// Round 3
// 335.583 us; speedup vs baseline: 1.0599x; 1.0418x over previous
//
#include <hip/hip_runtime.h>

#define FDIM 1000
#define BDIM 2049
#define NTH  256
#define FS   8           // f splits
#define FT   125         // f per block (FS*FT == FDIM)
#define BT   16          // b per block
#define NBT  129         // ceil(BDIM/BT)
#define GRID (NBT * FS)

// out layout (floats): y_out (F,B,C,2,S) | v (F,B,S) | R (B,C,C,2,S)
#define V_OFF 32784000ull
#define R_OFF 40980000ull

// ws layout (floats): part1[B][FS][20] | part2[B][FS][20]  (~2.6 MB total)
#define P2_OFF ((size_t)BDIM * FS * 20)

#define EPSF 1.1920928955078125e-07f
#define REGC 3.4526698300124393e-04f

// ---------------- K1: stream y -> v1, partial R1/sum(v1) ----------------
__global__ __launch_bounds__(NTH) void k1_power(
    const float* __restrict__ y, float* __restrict__ v, float* __restrict__ part1)
{
    const int btile = blockIdx.x / FS;
    const int fs    = blockIdx.x % FS;
    const int tid   = threadIdx.x;
    const int bs    = tid & 15;
    const int fi    = tid >> 4;
    const int wid   = tid >> 6;
    const int b     = btile * BT + bs;
    const bool vb   = (b < BDIM);

    float acc[20];
    #pragma unroll
    for (int j = 0; j < 20; ++j) acc[j] = 0.f;

    const int f0 = fs * FT;
    #pragma unroll
    for (int ii = 0; ii < 8; ++ii) {
        const int fo = ii * 16 + fi;
        if (fo < FT && vb) {
            const int f = f0 + fo;
            const size_t e = (size_t)f * BDIM + b;
            const float4* yp = reinterpret_cast<const float4*>(y) + e * 4;
            float4 a0 = yp[0], a1 = yp[1], a2 = yp[2], a3 = yp[3];
            float y0r[4] = {a0.x,a0.y,a0.z,a0.w};
            float y0i[4] = {a1.x,a1.y,a1.z,a1.w};
            float y1r[4] = {a2.x,a2.y,a2.z,a2.w};
            float y1i[4] = {a3.x,a3.y,a3.z,a3.w};
            float vv[4];
            #pragma unroll
            for (int s = 0; s < 4; ++s) {
                const float p0 = y0r[s]*y0r[s] + y0i[s]*y0i[s];
                const float p1 = y1r[s]*y1r[s] + y1i[s]*y1i[s];
                vv[s] = 0.5f * (p0 + p1);
                acc[s]    += p0;
                acc[4+s]  += p1;
                acc[8+s]  += y0r[s]*y1r[s] + y0i[s]*y1i[s];
                acc[12+s] += y0i[s]*y1r[s] - y0r[s]*y1i[s];
                acc[16+s] += vv[s];
            }
            reinterpret_cast<float4*>(v)[e] = make_float4(vv[0], vv[1], vv[2], vv[3]);
        }
    }
    #pragma unroll
    for (int j = 0; j < 20; ++j) {
        float t = acc[j];
        t += __shfl_xor(t, 16);
        t += __shfl_xor(t, 32);
        acc[j] = t;
    }
    __shared__ float red[4][16][20];
    if ((tid & 63) < 16) {
        #pragma unroll
        for (int j = 0; j < 20; ++j) red[wid][bs][j] = acc[j];
    }
    __syncthreads();
    for (int idx = tid; idx < 320; idx += NTH) {
        const int bss = idx & 15, j = idx >> 4;
        const int bb = btile * BT + bss;
        if (bb < BDIM)
            part1[((size_t)bb * FS + fs) * 20 + j] =
                red[0][bss][j] + red[1][bss][j] + red[2][bss][j] + red[3][bss][j];
    }
}

// ---------------- K3: v1,x -> yc1 (on the fly) -> v2, partial R2 ----------------
__global__ __launch_bounds__(NTH) void k3_em(
    const float* __restrict__ x, float* __restrict__ v,
    const float* __restrict__ part1, float* __restrict__ part2,
    const int* __restrict__ itp)
{
    const int btile = blockIdx.x / FS;
    const int fs    = blockIdx.x % FS;
    const int tid   = threadIdx.x;
    const int bs    = tid & 15;
    const int fi    = tid >> 4;
    const int wid   = tid >> 6;
    const int b     = btile * BT + bs;
    const bool vb   = (b < BDIM);
    const int iters = itp[0];

    __shared__ float rsumS[16][20];
    __shared__ float rnormS[16][16];
    for (int idx = tid; idx < 320; idx += NTH) {
        const int bss = idx & 15, j = idx >> 4;
        const int bb = btile * BT + bss;
        float s = 0.f;
        if (bb < BDIM) {
            #pragma unroll
            for (int q = 0; q < FS; ++q) s += part1[((size_t)bb * FS + q) * 20 + j];
        }
        rsumS[bss][j] = s;
    }
    __syncthreads();
    {
        const int bss = tid & 15, j = tid >> 4;   // j 0..15
        rnormS[bss][j] = rsumS[bss][j] / (EPSF + rsumS[bss][16 + (j & 3)]);
    }
    __syncthreads();

    if (iters <= 1) {   // pass-through: R stays R1, v stays v1
        for (int idx = tid; idx < 320; idx += NTH) {
            const int bss = idx & 15, j = idx >> 4;
            const int bb = btile * BT + bss;
            if (bb < BDIM)
                part2[((size_t)bb * FS + fs) * 20 + j] = (fs == 0) ? rsumS[bss][j] : 0.f;
        }
        return;
    }

    float rn00[4], rn11[4], rn01r[4], rn01i[4];
    #pragma unroll
    for (int s = 0; s < 4; ++s) {
        rn00[s]=rnormS[bs][s]; rn11[s]=rnormS[bs][4+s];
        rn01r[s]=rnormS[bs][8+s]; rn01i[s]=rnormS[bs][12+s];
    }

    float acc[20];
    #pragma unroll
    for (int j = 0; j < 20; ++j) acc[j] = 0.f;

    const int f0 = fs * FT;
    #pragma unroll
    for (int ii = 0; ii < 8; ++ii) {
        const int fo = ii * 16 + fi;
        if (fo < FT && vb) {
            const int f = f0 + fo;
            const size_t e = (size_t)f * BDIM + b;
            float4 vv4 = reinterpret_cast<const float4*>(v)[e];
            float4 xv  = reinterpret_cast<const float4*>(x)[e];
            float v1[4] = {vv4.x, vv4.y, vv4.z, vv4.w};
            float c00 = REGC, c11 = REGC, c01r = 0.f, c01i = 0.f;
            #pragma unroll
            for (int s = 0; s < 4; ++s) {
                c00  += v1[s]*rn00[s];
                c11  += v1[s]*rn11[s];
                c01r += v1[s]*rn01r[s];
                c01i += v1[s]*rn01i[s];
            }
            const float det  = c00*c11 - (c01r*c01r + c01i*c01i);
            const float invd = det / (det*det);
            const float i00 = invd*c11, i11 = invd*c00;
            const float i01r = -invd*c01r, i01i = -invd*c01i;
            const float xr0 = xv.x, xi0 = xv.y, xr1 = xv.z, xi1 = xv.w;
            const float w0r = i00*xr0 + (i01r*xr1 - i01i*xi1);
            const float w0i = i00*xi0 + (i01r*xi1 + i01i*xr1);
            const float w1r = (i01r*xr0 + i01i*xi0) + i11*xr1;
            const float w1i = (i01r*xi0 - i01i*xr0) + i11*xi1;
            float v2[4];
            #pragma unroll
            for (int s = 0; s < 4; ++s) {
                const float vs = v1[s];
                const float y0r = vs*(rn00[s]*w0r + (rn01r[s]*w1r - rn01i[s]*w1i));
                const float y0i = vs*(rn00[s]*w0i + (rn01r[s]*w1i + rn01i[s]*w1r));
                const float y1r = vs*((rn01r[s]*w0r + rn01i[s]*w0i) + rn11[s]*w1r);
                const float y1i = vs*((rn01r[s]*w0i - rn01i[s]*w0r) + rn11[s]*w1i);
                const float p0 = y0r*y0r + y0i*y0i;
                const float p1 = y1r*y1r + y1i*y1i;
                v2[s] = 0.5f*(p0 + p1);
                acc[s]    += p0;
                acc[4+s]  += p1;
                acc[8+s]  += y0r*y1r + y0i*y1i;
                acc[12+s] += y0i*y1r - y0r*y1i;
                acc[16+s] += v2[s];
            }
            reinterpret_cast<float4*>(v)[e] = make_float4(v2[0], v2[1], v2[2], v2[3]);
        }
    }
    #pragma unroll
    for (int j = 0; j < 20; ++j) {
        float t = acc[j];
        t += __shfl_xor(t, 16);
        t += __shfl_xor(t, 32);
        acc[j] = t;
    }
    __shared__ float red[4][16][20];
    if ((tid & 63) < 16) {
        #pragma unroll
        for (int j = 0; j < 20; ++j) red[wid][bs][j] = acc[j];
    }
    __syncthreads();
    for (int idx = tid; idx < 320; idx += NTH) {
        const int bss = idx & 15, j = idx >> 4;
        const int bb = btile * BT + bss;
        if (bb < BDIM)
            part2[((size_t)bb * FS + fs) * 20 + j] =
                red[0][bss][j] + red[1][bss][j] + red[2][bss][j] + red[3][bss][j];
    }
}

// ---------------- K5: v2,x -> yc2 -> y_out; R_out ----------------
__global__ __launch_bounds__(NTH) void k5_final(
    const float* __restrict__ y, const float* __restrict__ x, const float* __restrict__ v,
    const float* __restrict__ part2, float* __restrict__ yout, float* __restrict__ Rout,
    const int* __restrict__ itp)
{
    const int btile = blockIdx.x / FS;
    const int fs    = blockIdx.x % FS;
    const int tid   = threadIdx.x;
    const int bs    = tid & 15;
    const int fi    = tid >> 4;
    const int b     = btile * BT + bs;
    const bool vb   = (b < BDIM);
    const int iters = itp[0];

    __shared__ float rsumS[16][20];
    __shared__ float rnormS[16][16];
    for (int idx = tid; idx < 320; idx += NTH) {
        const int bss = idx & 15, j = idx >> 4;
        const int bb = btile * BT + bss;
        float s = 0.f;
        if (bb < BDIM) {
            #pragma unroll
            for (int q = 0; q < FS; ++q) s += part2[((size_t)bb * FS + q) * 20 + j];
        }
        rsumS[bss][j] = s;
    }
    __syncthreads();
    {
        const int bss = tid & 15, j = tid >> 4;
        rnormS[bss][j] = rsumS[bss][j] / (EPSF + rsumS[bss][16 + (j & 3)]);
    }
    __syncthreads();

    if (fs == 0) {   // R_out
        for (int idx = tid; idx < 512; idx += NTH) {
            const int bss = idx >> 5, r = idx & 31;
            const int bb = btile * BT + bss;
            if (bb < BDIM) {
                const int c = (r>>4)&1, d = (r>>3)&1, ri = (r>>2)&1, s = r&3;
                const bool raw = (iters == 0);
                float val;
                if (c == d) {
                    val = ri ? 0.f : (raw ? rsumS[bss][(c?4:0)+s] : rnormS[bss][(c?4:0)+s]);
                } else {
                    const float re = raw ? rsumS[bss][8+s]  : rnormS[bss][8+s];
                    const float im = raw ? rsumS[bss][12+s] : rnormS[bss][12+s];
                    val = ri ? (c == 0 ? im : -im) : re;
                }
                Rout[(size_t)bb * 32 + r] = val;
            }
        }
    }

    const int f0 = fs * FT;
    if (iters == 0) {   // y_out = y
        #pragma unroll
        for (int ii = 0; ii < 8; ++ii) {
            const int fo = ii * 16 + fi;
            if (fo < FT && vb) {
                const size_t e = (size_t)(f0 + fo) * BDIM + b;
                const float4* yp = reinterpret_cast<const float4*>(y) + e * 4;
                float4* op = reinterpret_cast<float4*>(yout) + e * 4;
                op[0] = yp[0]; op[1] = yp[1]; op[2] = yp[2]; op[3] = yp[3];
            }
        }
        return;
    }

    float rn00[4], rn11[4], rn01r[4], rn01i[4];
    #pragma unroll
    for (int s = 0; s < 4; ++s) {
        rn00[s]=rnormS[bs][s]; rn11[s]=rnormS[bs][4+s];
        rn01r[s]=rnormS[bs][8+s]; rn01i[s]=rnormS[bs][12+s];
    }

    #pragma unroll
    for (int ii = 0; ii < 8; ++ii) {
        const int fo = ii * 16 + fi;
        if (fo < FT && vb) {
            const int f = f0 + fo;
            const size_t e = (size_t)f * BDIM + b;
            float4 vv4 = reinterpret_cast<const float4*>(v)[e];
            float4 xv  = reinterpret_cast<const float4*>(x)[e];
            float vcur[4] = {vv4.x, vv4.y, vv4.z, vv4.w};
            float c00 = REGC, c11 = REGC, c01r = 0.f, c01i = 0.f;
            #pragma unroll
            for (int s = 0; s < 4; ++s) {
                c00  += vcur[s]*rn00[s];
                c11  += vcur[s]*rn11[s];
                c01r += vcur[s]*rn01r[s];
                c01i += vcur[s]*rn01i[s];
            }
            const float det  = c00*c11 - (c01r*c01r + c01i*c01i);
            const float invd = det / (det*det);
            const float i00 = invd*c11, i11 = invd*c00;
            const float i01r = -invd*c01r, i01i = -invd*c01i;
            const float xr0 = xv.x, xi0 = xv.y, xr1 = xv.z, xi1 = xv.w;
            const float w0r = i00*xr0 + (i01r*xr1 - i01i*xi1);
            const float w0i = i00*xi0 + (i01r*xi1 + i01i*xr1);
            const float w1r = (i01r*xr0 + i01i*xi0) + i11*xr1;
            const float w1i = (i01r*xi0 - i01i*xr0) + i11*xi1;
            float o0r[4], o0i[4], o1r[4], o1i[4];
            #pragma unroll
            for (int s = 0; s < 4; ++s) {
                const float vs = vcur[s];
                o0r[s] = vs*(rn00[s]*w0r + (rn01r[s]*w1r - rn01i[s]*w1i));
                o0i[s] = vs*(rn00[s]*w0i + (rn01r[s]*w1i + rn01i[s]*w1r));
                o1r[s] = vs*((rn01r[s]*w0r + rn01i[s]*w0i) + rn11[s]*w1r);
                o1i[s] = vs*((rn01r[s]*w0i - rn01i[s]*w0r) + rn11[s]*w1i);
            }
            float4* op = reinterpret_cast<float4*>(yout) + e * 4;
            op[0] = make_float4(o0r[0], o0r[1], o0r[2], o0r[3]);
            op[1] = make_float4(o0i[0], o0i[1], o0i[2], o0i[3]);
            op[2] = make_float4(o1r[0], o1r[1], o1r[2], o1r[3]);
            op[3] = make_float4(o1i[0], o1i[1], o1i[2], o1i[3]);
        }
    }
}

extern "C" void kernel_launch(void* const* d_in, const int* in_sizes, int n_in,
                              void* d_out, int out_size, void* d_ws, size_t ws_size,
                              hipStream_t stream) {
    const float* y   = (const float*)d_in[0];
    const float* x   = (const float*)d_in[1];
    const int*   itp = (const int*)d_in[2];
    float* out   = (float*)d_out;
    float* vreg  = out + V_OFF;
    float* Rreg  = out + R_OFF;
    float* part1 = (float*)d_ws;
    float* part2 = part1 + P2_OFF;

    k1_power<<<GRID, NTH, 0, stream>>>(y, vreg, part1);
    k3_em   <<<GRID, NTH, 0, stream>>>(x, vreg, part1, part2, itp);
    k5_final<<<GRID, NTH, 0, stream>>>(y, x, vreg, part2, out, Rreg, itp);
}